// Round 9
// baseline (344.792 us; speedup 1.0000x reference)
//
#include <hip/hip_runtime.h>
#include <math.h>

typedef __attribute__((ext_vector_type(8))) short bf16x8;
typedef __attribute__((ext_vector_type(4))) float f32x4;
typedef __attribute__((ext_vector_type(2))) float f32x2;

#define HEADS 32
#define SEQT  8192
#define DIM   128
#define NQ    16
#define BPH   64            // blocks per head
#define BTOK  128           // tokens per block
#define WTOK  32            // tokens per wave
#define CHK   16            // tokens per chunk (one MFMA tile)
#define NPART BPH
#define PSTR  132           // floats per q-row in partial: [m,l,pad,pad, acc(128)]
#define QSCALE 0.08838834764831845f  // 1/sqrt(128)

// LDS layout (bytes) — total 40960 = 4 blocks/CU (160 KiB / 40960 = 4)
#define OFF_QS    0          // 16*128*2  = 4096 (dead after qa load)
#define OFF_PS    4096       // 4*16*16*4 = 4096
#define OFF_RAW   8192       // 4 waves * 4096 = 16384 (raw 8-tok granule)
#define OFF_KS    24576      // 4 waves * 4096 = 16384 (K bf16 [16][128] swz; V f32 [8][128] swz overlays)
#define OFF_ML    0          // overlay on dead Qs (512 B)
#define OFF_MERGE 8192       // overlay on RAW (needs 16384, exact fit)
#define LDS_BYTES 40960

// quantization constants: Tk = cos((k-0.5)*pi/7) thresholds, squared; sin/cos(k*pi/7)
#define W1SQ 0.9504844339512096f   // cos^2(pi/14)
#define W2SQ 0.6112604669781572f   // cos^2(3pi/14)
#define W3SQ 0.1882550990706332f   // cos^2(5pi/14)
#define S1C  0.4338837391175581f   // sin(pi/7)
#define S2C  0.7818314824680298f   // sin(2pi/7)
#define S3C  0.9749279121818236f   // sin(3pi/7)
#define C1C  0.9009688679024191f   // cos(pi/7)
#define C2C  0.6234898018587336f   // cos(2pi/7)
#define C3C  0.2225209339563144f   // cos(3pi/7)
// last-angle (2*pi range) thresholds: cos((2k+1)pi/7), squared
#define B1SQ 0.8117449009293667f   // cos^2(pi/7)
#define B2SQ 0.0495155660487913f   // cos^2(3pi/7)
#define B3SQ 0.3887395330218429f   // cos^2(5pi/7)

// DPP controls
#define DPP_QP_XOR1 0xB1   // quad_perm(1,0,3,2)
#define DPP_QP_XOR2 0x4E   // quad_perm(2,3,0,1)
#define DPP_QP_SHL1 0x39   // quad_perm(1,2,3,0)
#define DPP_QP_SHR1 0x90   // quad_perm(0,0,1,2)
#define DPP_QP_SHR2 0x44   // quad_perm(0,1,0,1)
#define DPP_QP_BC0  0x00   // quad_perm(0,0,0,0)
#define DPP_QP_BC3  0xFF   // quad_perm(3,3,3,3)
#define DPP_HALF_MIRR 0x141  // i ^ 7 within row
#define DPP_MIRR      0x140  // i ^ 15 within row

#define WAITV asm volatile("s_waitcnt vmcnt(0)" ::: "memory")

template <int CTRL>
__device__ __forceinline__ float dpp0(float v) {
  return __int_as_float(__builtin_amdgcn_update_dpp(
      0, __float_as_int(v), CTRL, 0xF, 0xF, true));
}
// 16-lane-row butterfly reductions (softmax) — pure VALU
__device__ __forceinline__ float rmax16(float v) {
  v = fmaxf(v, dpp0<DPP_QP_XOR1>(v));
  v = fmaxf(v, dpp0<DPP_QP_XOR2>(v));
  v = fmaxf(v, dpp0<DPP_HALF_MIRR>(v));
  v = fmaxf(v, dpp0<DPP_MIRR>(v));
  return v;
}
__device__ __forceinline__ float rsum16(float v) {
  v += dpp0<DPP_QP_XOR1>(v);
  v += dpp0<DPP_QP_XOR2>(v);
  v += dpp0<DPP_HALF_MIRR>(v);
  v += dpp0<DPP_MIRR>(v);
  return v;
}
__device__ __forceinline__ float rdlane(float v, int l) {
  return __int_as_float(__builtin_amdgcn_readlane(__float_as_int(v), l));
}
__device__ __forceinline__ unsigned short f2bf(float f) {
  unsigned u = __float_as_uint(f);
  u += 0x7FFFu + ((u >> 16) & 1u);  // RNE
  return (unsigned short)(u >> 16);
}
__device__ __forceinline__ unsigned cvtpk(float lo, float hi) {
  unsigned r;
  asm("v_cvt_pk_bf16_f32 %0, %1, %2" : "=v"(r) : "v"(lo), "v"(hi));
  return r;
}

// Stage 8 tokens (4 KB) of raw fp32 into LDS via global_load_lds.
// LDS dest linear (base + lane*16 per instr); per-lane GLOBAL source is
// XOR-swizzled: phys 16B-slot (t, s) holds logical slot (t, (s&0x18)|((s&7)^t)).
__device__ __forceinline__ void stage8(const float* __restrict__ g, char* lds, int lane) {
  const int h2 = lane >> 5;
  const int qs = (lane >> 3) & 3;
  const int js = lane & 7;
#pragma unroll
  for (int i = 0; i < 4; ++i) {
    const int t = 2 * i + h2;                 // t in 0..7
    const int sb = js ^ t;
    __builtin_amdgcn_global_load_lds(
        (const float*)(g + (size_t)t * DIM + qs * 32 + sb * 4),
        (float*)(lds + i * 1024), 16, 0, 0);
  }
}

// Per-lane polar compress+decompress of 8 tokens (one raw granule).
// lane = (token tloc = lane>>3, 16-dim slice o = lane&7). No readlane, no
// data-dependent LDS, no divergence. Register-slim variant (R8 lesson):
// the per-dim quantization compare-tree is RECOMPUTED in stage 2 instead of
// carrying sv[16]/cv[16] across the stitch (-32 VGPRs; identical float
// sequence -> bit-identical results). K out: bf16 [16][128] rows q8*8+tloc,
// XOR-swizzled ^(tloc<<3) (ushort units). V out: f32 [8][128] rows tloc,
// XOR-swizzled ^(tloc<<2) (float units).
template <bool KOUT>
__device__ __forceinline__ void decomp8(
    const float* rawW, int lane,
    unsigned short* KsW, float* VsW, int q8,
    const float* nextsrc, char* rawBytes)
{
  const int tloc = lane >> 3;       // token within granule (0..7)
  const int o    = lane & 7;        // 16-dim slice

  // ---- load own 16 dims (swizzled slots)
  float x[16];
#pragma unroll
  for (int j = 0; j < 4; ++j) {
    const int s = ((o >> 1) << 3) | ((((o & 1) << 2) | j) ^ tloc);
    const float4 v = *(const float4*)(rawW + tloc * 128 + 4 * s);
    x[4*j+0] = v.x; x[4*j+1] = v.y; x[4*j+2] = v.z; x[4*j+3] = v.w;
  }
  // raw fully in registers before the next granule's DMA may overwrite it
  asm volatile("s_waitcnt lgkmcnt(0)" ::: "memory");
  __builtin_amdgcn_sched_barrier(0);
  if (nextsrc) stage8(nextsrc, rawBytes, lane);
  __builtin_amdgcn_sched_barrier(0);

  // ---- pass A: per-lane sum of squares, 8-lane suffix stitch (DPP only)
  float qa0 = 0.f, qa1 = 0.f;
#pragma unroll
  for (int i = 0; i < 16; i += 2) {
    qa0 = fmaf(x[i], x[i], qa0);
    qa1 = fmaf(x[i+1], x[i+1], qa1);
  }
  const float qs = qa0 + qa1;
  const float a1 = dpp0<DPP_QP_SHL1>(qs);
  const float t1 = qs + (((lane & 3) == 3) ? 0.f : a1);
  const float b1 = dpp0<DPP_QP_XOR2>(t1);
  const float t2 = t1 + (((lane & 3) < 2) ? b1 : 0.f);      // quad suffix-incl
  const float qt = dpp0<DPP_QP_BC0>(t2);                    // own quad total
  const float ot = dpp0<DPP_HALF_MIRR>(qt);                 // other quad total
  const float total = qt + ot;
  const float S = t2 + ((o < 4) ? ot : 0.f);                // suffix-incl across 8

  const float r = sqrtf(total);

  // ---- stage 1: per-lane sin-product only (sv/cv NOT stored — recomputed)
  float run = S, psin = 1.f;
#pragma unroll
  for (int i = 0; i < 16; ++i) {
    const float u = x[i] * x[i];
    const bool lo2 = u < W2SQ * run;          // |c| < T2  -> s in {2,3}
    const float thr = lo2 ? W3SQ : W1SQ;
    const bool bx = u < thr * run;
    const float ssin = lo2 ? (bx ? S3C : S2C) : (bx ? S1C : 0.f);
    psin *= ssin;
    run -= u;
  }
  // ---- 8-lane exclusive prefix-product stitch (DPP only)
  const float p1 = dpp0<DPP_QP_SHR1>(psin);
  const float e1 = psin * (((lane & 3) == 0) ? 1.f : p1);
  const float p2 = dpp0<DPP_QP_SHR2>(e1);
  const float e2 = e1 * (((lane & 3) < 2) ? 1.f : p2);      // quad prefix-incl
  const float pq = dpp0<DPP_QP_BC3>(e2);                    // own quad product
  const float po = dpp0<DPP_HALF_MIRR>(pq);                 // other quad product
  const float e3 = e2 * ((o >= 4) ? po : 1.f);              // full prefix-incl
  const float sh = dpp0<DPP_QP_SHR1>(e3);
  const float E = ((lane & 3) == 0) ? ((o < 4) ? 1.f : po) : sh;  // exclusive

  // ---- stage 2: recompute quantization per dim and emit outputs
  float rcum = r * E;
  float run2 = S;
  float run14 = 0.f, rc14 = 0.f;
  const int T = q8 * 8 + tloc;
#pragma unroll
  for (int g = 0; g < 2; ++g) {
    float outv[8];
#pragma unroll
    for (int k = 0; k < 8; ++k) {
      const int i = 8 * g + k;
      const float u = x[i] * x[i];
      if (i == 14) { run14 = run2; rc14 = rcum; }  // state at dim 126 (o==7 tail)
      const bool lo2 = u < W2SQ * run2;
      const float thr = lo2 ? W3SQ : W1SQ;
      const bool bx = u < thr * run2;
      const float ssin = lo2 ? (bx ? S3C : S2C) : (bx ? S1C : 0.f);
      float scos = lo2 ? (bx ? C3C : C2C) : (bx ? C1C : 1.f);
      scos = copysignf(scos, x[i]);             // idx >= 4 <=> x<0 <=> cos flips
      outv[k] = rcum * scos;
      rcum *= ssin;
      run2 -= u;
    }
    if (g == 1) {
      // last angle has 2*pi range: idx from c126 thresholds, sign from x127
      const float u14 = x[14] * x[14];
      const bool neg = x[14] < 0.f;
      const bool cc1 = u14 < B1SQ * run14;
      const bool cc2 = u14 < B2SQ * run14;
      const bool cc3 = u14 > B3SQ * run14;
      const float cpos = cc2 ? -C3C : (cc1 ? C2C : 1.f);
      const float spos = cc2 ? S3C : (cc1 ? S2C : 0.f);
      const float cneg = cc3 ? -C1C : -C3C;
      const float sneg = cc3 ? S1C : S3C;
      const float cB = neg ? cneg : cpos;
      float sB = neg ? sneg : spos;
      sB = copysignf(sB, x[15]);
      const bool o7 = (o == 7);
      outv[6] = o7 ? rc14 * cB : outv[6];
      outv[7] = o7 ? rc14 * sB : outv[7];
    }
    if (KOUT) {
      uint4 w;
      w.x = cvtpk(outv[0], outv[1]);
      w.y = cvtpk(outv[2], outv[3]);
      w.z = cvtpk(outv[4], outv[5]);
      w.w = cvtpk(outv[6], outv[7]);
      // ushort idx: T*128 + ((o*16 + 8g) ^ (tloc<<3)) — 16B aligned
      *(uint4*)&KsW[T * 128 + ((o * 16 + 8 * g) ^ (tloc << 3))] = w;
    } else {
      // float idx: tloc*128 + ((o*16 + 8g + {0,4}) ^ (tloc<<2)) — 16B aligned
      const int f0 = (o * 16 + 8 * g) ^ (tloc << 2);
      *(float4*)&VsW[tloc * 128 + f0]       = make_float4(outv[0], outv[1], outv[2], outv[3]);
      *(float4*)&VsW[tloc * 128 + (f0 ^ 4)] = make_float4(outv[4], outv[5], outv[6], outv[7]);
    }
  }
}

__global__ __launch_bounds__(256, 4)   // 128-total reg cap; fits after sv/cv removal
                                       // (R7 lesson: this cap + sv/cv arrays => 270MB scratch spill)
void attn_partial(const float* __restrict__ Q, const float* __restrict__ K,
                  const float* __restrict__ V, const float* __restrict__ noise,
                  float* __restrict__ part) {
  __shared__ __align__(16) char RAW[LDS_BYTES];
  unsigned short* Qs = (unsigned short*)(RAW + OFF_QS);
  float*          Ps = (float*)(RAW + OFF_PS);
  float2*         Ml = (float2*)(RAW + OFF_ML);   // overlays dead Qs

  const int tid  = threadIdx.x;
  const int lane = tid & 63;
  const int wv   = tid >> 6;
  const int h    = blockIdx.x / BPH;
  const int bh   = blockIdx.x % BPH;
  const int r16  = lane & 15, G = lane >> 4;

  char* rawB = RAW + OFF_RAW + wv * 4096;
  const float* rawW = (const float*)rawB;
  unsigned short* KsW = (unsigned short*)(RAW + OFF_KS + wv * 4096);
  float* VsW = (float*)KsW;            // overlay: Ks dead after scores
  float* myP = Ps + wv * (CHK * NQ);

  const size_t hoff = (size_t)h * SEQT * DIM;
  const int t0 = bh * BTOK + wv * WTOK;
  const float* Kg = K + hoff + (size_t)t0 * DIM;
  const float* Vg = V + hoff + (size_t)t0 * DIM;

  // prologue: prefetch K granule 0 (tokens 0..7) while staging Q
  stage8(Kg, rawB, lane);
  {
    const float* Qh = Q + (size_t)h * NQ * DIM;
    for (int i = tid; i < NQ * DIM; i += 256)
      Qs[i] = f2bf(Qh[i] * QSCALE);
  }
  __syncthreads();   // Q ready; barrier drain also lands granule 0 (one-time)

  bf16x8 qa[4];
#pragma unroll
  for (int c = 0; c < 4; ++c)
    qa[c] = *(const bf16x8*)&Qs[r16 * 128 + c * 32 + G * 8];

  f32x2 acc[NQ];
#pragma unroll
  for (int qq = 0; qq < NQ; ++qq) acc[qq] = (f32x2){0.f, 0.f};
  float m_r[4] = {-INFINITY, -INFINITY, -INFINITY, -INFINITY};
  float l_r[4] = {0.f, 0.f, 0.f, 0.f};

  const float* nh = noise + (size_t)h * NQ * SEQT + t0 + r16;

#pragma unroll 1
  for (int ch = 0; ch < 2; ++ch) {
    const float* KgC = Kg + ch * 2048;   // 16 tokens * 128 floats per chunk
    const float* VgC = Vg + ch * 2048;

    // ---- K decompress -> Ks bf16 (2 granules); stage pipeline 1 ahead
    WAITV;
    decomp8<true>(rawW, lane, KsW, VsW, 0, KgC + 1024, rawB);  // stage K tok 8..15 of chunk
    WAITV;
    decomp8<true>(rawW, lane, KsW, VsW, 1, VgC, rawB);         // stage V tok 0..7 of chunk

    // ---- scores via MFMA, K=128 chained (Ks XOR-swizzled read)
    f32x4 d0 = {0.f, 0.f, 0.f, 0.f};
#pragma unroll
    for (int c = 0; c < 4; ++c) {
      bf16x8 b0 = *(const bf16x8*)&KsW[r16 * 128 + ((c * 32 + G * 8) ^ ((r16 & 7) << 3))];
      d0 = __builtin_amdgcn_mfma_f32_16x16x32_bf16(qa[c], b0, d0, 0, 0, 0);
    }
    const float* nt = nh + ch * CHK;
    float s0_[4];
#pragma unroll
    for (int rr = 0; rr < 4; ++rr)
      s0_[rr] = d0[rr] + nt[(size_t)(4 * G + rr) * SEQT];
    // ---- online softmax (quad G owns queries 4G..4G+3)
    float al_r[4];
#pragma unroll
    for (int rr = 0; rr < 4; ++rr) {
      float mt = rmax16(s0_[rr]);
      float mn = fmaxf(m_r[rr], mt);
      al_r[rr] = __expf(m_r[rr] - mn);
      m_r[rr] = mn;
    }
    float p0[4];
#pragma unroll
    for (int rr = 0; rr < 4; ++rr) {
      p0[rr] = __expf(s0_[rr] - m_r[rr]);
      l_r[rr] = l_r[rr] * al_r[rr] + rsum16(p0[rr]);
    }
    *(float4*)&myP[r16 * NQ + 4 * G] = make_float4(p0[0], p0[1], p0[2], p0[3]);
#pragma unroll
    for (int qq = 0; qq < NQ; ++qq) {
      float alq = rdlane(al_r[qq & 3], (qq >> 2) << 4);
      acc[qq] *= (f32x2){alq, alq};    // v_pk_mul_f32
    }

    // ---- V decompress (f32 -> Vs, overlays Ks) + PV, per 8-token granule
#pragma unroll 1
    for (int sc = 0; sc < 2; ++sc) {
      // sc=0: stage V tok 8..15 of chunk; sc=1: stage NEXT chunk's K tok 0..7
      const float* nxt = (sc == 0) ? (VgC + 1024)
                                   : ((ch == 0) ? (KgC + 2048) : nullptr);
      WAITV;
      decomp8<false>(rawW, lane, KsW, VsW, 0, nxt, rawB);
#pragma unroll 2
      for (int tt = 0; tt < 8; ++tt) {
        float2 vh = *(const float2*)&VsW[tt * 128 + ((2 * lane) ^ (tt << 2))];
        f32x2 vh2 = {vh.x, vh.y};
        const float* pv = &myP[(sc * 8 + tt) * NQ];
        float4 pa = ((const float4*)pv)[0];
        float4 pb = ((const float4*)pv)[1];
        float4 pc = ((const float4*)pv)[2];
        float4 pd = ((const float4*)pv)[3];
        float pq[NQ] = {pa.x, pa.y, pa.z, pa.w, pb.x, pb.y, pb.z, pb.w,
                        pc.x, pc.y, pc.z, pc.w, pd.x, pd.y, pd.z, pd.w};
#pragma unroll
        for (int qq = 0; qq < NQ; ++qq)
          acc[qq] = __builtin_elementwise_fma((f32x2){pq[qq], pq[qq]}, vh2, acc[qq]);
      }
    }
  }

  // ---- block-level merge of the 4 wave states (online-softmax combine)
  if (r16 == 0) {
#pragma unroll
    for (int rr = 0; rr < 4; ++rr)
      Ml[wv * NQ + 4 * G + rr] = make_float2(m_r[rr], l_r[rr]);
  }
  __syncthreads();   // fences last raw/Vs use before overlays
#pragma unroll
  for (int qq = 0; qq < NQ; ++qq) {
    float2 e0 = Ml[0 * NQ + qq], e1 = Ml[1 * NQ + qq];
    float2 e2 = Ml[2 * NQ + qq], e3 = Ml[3 * NQ + qq];
    float Mq = fmaxf(fmaxf(e0.x, e1.x), fmaxf(e2.x, e3.x));
    float own = (wv == 0) ? e0.x : ((wv == 1) ? e1.x : ((wv == 2) ? e2.x : e3.x));
    float al = __expf(own - Mq);
    acc[qq] *= (f32x2){al, al};
  }
  float* buf = (float*)(RAW + OFF_MERGE);   // overlays RAW (16384 B)
  if (wv >= 2) {
#pragma unroll
    for (int qq = 0; qq < NQ; ++qq)
      *(float2*)&buf[(wv - 2) * 2048 + qq * 128 + 2 * lane] =
          make_float2(acc[qq].x, acc[qq].y);
  }
  __syncthreads();
  if (wv < 2) {
#pragma unroll
    for (int qq = 0; qq < NQ; ++qq) {
      float2 t = *(const float2*)&buf[wv * 2048 + qq * 128 + 2 * lane];
      acc[qq] += (f32x2){t.x, t.y};
    }
  }
  __syncthreads();
  if (wv == 1) {
#pragma unroll
    for (int qq = 0; qq < NQ; ++qq)
      *(float2*)&buf[qq * 128 + 2 * lane] = make_float2(acc[qq].x, acc[qq].y);
  }
  __syncthreads();
  if (wv == 0) {
    float* P = part + ((size_t)h * NPART + bh) * (NQ * PSTR);
#pragma unroll
    for (int qq = 0; qq < NQ; ++qq) {
      float2 t = *(const float2*)&buf[qq * 128 + 2 * lane];
      *(float2*)&P[qq * PSTR + 4 + 2 * lane] =
          make_float2(acc[qq].x + t.x, acc[qq].y + t.y);
      float2 e0 = Ml[0 * NQ + qq], e1 = Ml[1 * NQ + qq];
      float2 e2 = Ml[2 * NQ + qq], e3 = Ml[3 * NQ + qq];
      float Mq = fmaxf(fmaxf(e0.x, e1.x), fmaxf(e2.x, e3.x));
      float Lq = e0.y * __expf(e0.x - Mq) + e1.y * __expf(e1.x - Mq) +
                 e2.y * __expf(e2.x - Mq) + e3.y * __expf(e3.x - Mq);
      if (lane == 0) *(float2*)&P[qq * PSTR] = make_float2(Mq, Lq);
    }
  }
}

__global__ __launch_bounds__(128)
void attn_reduce(const float* __restrict__ part, float* __restrict__ out) {
  __shared__ float wgt[NPART];
  __shared__ float Lsh;
  const int tid = threadIdx.x;
  const int h = blockIdx.x >> 4;
  const int q = blockIdx.x & 15;
  const float* P = part + (size_t)h * NPART * NQ * PSTR;
  if (tid < NPART) {
    float2 ml = *(const float2*)&P[((size_t)tid * NQ + q) * PSTR];
    float M = ml.x;
#pragma unroll
    for (int off = 1; off < 64; off <<= 1)
      M = fmaxf(M, __shfl_xor(M, off, 64));
    float w = __expf(ml.x - M);
    wgt[tid] = w;
    float L = ml.y * w;
#pragma unroll
    for (int off = 1; off < 64; off <<= 1)
      L += __shfl_xor(L, off, 64);
    if (tid == 0) Lsh = L;
  }
  __syncthreads();
  const float* A = P + (size_t)q * PSTR + 4 + tid;
  float o = 0.f;
#pragma unroll 8
  for (int c = 0; c < NPART; ++c)
    o = fmaf(wgt[c], A[(size_t)c * NQ * PSTR], o);
  out[((size_t)h * NQ + q) * DIM + tid] = o * (1.0f / Lsh);
}

extern "C" void kernel_launch(void* const* d_in, const int* in_sizes, int n_in,
                              void* d_out, int out_size, void* d_ws, size_t ws_size,
                              hipStream_t stream) {
  (void)in_sizes; (void)n_in; (void)out_size; (void)ws_size;
  const float* Q = (const float*)d_in[0];
  const float* K = (const float*)d_in[1];
  const float* V = (const float*)d_in[2];
  const float* noise = (const float*)d_in[3];
  float* part = (float*)d_ws;  // 32*64*16*132*4 B = 17.3 MB
  attn_partial<<<dim3(HEADS * BPH), dim3(256), 0, stream>>>(Q, K, V, noise, part);
  attn_reduce<<<dim3(HEADS * NQ), dim3(128), 0, stream>>>(part, (float*)d_out);
}

// Round 10
// 309.490 us; speedup vs baseline: 1.1141x; 1.1141x over previous
//
#include <hip/hip_runtime.h>
#include <math.h>

typedef __attribute__((ext_vector_type(8))) short bf16x8;
typedef __attribute__((ext_vector_type(4))) float f32x4;
typedef __attribute__((ext_vector_type(2))) float f32x2;

#define HEADS 32
#define SEQT  8192
#define DIM   128
#define NQ    16
#define BPH   64            // blocks per head
#define BTOK  128           // tokens per block
#define WTOK  32            // tokens per wave
#define CHK   16            // tokens per chunk (one MFMA tile)
#define NPART BPH
#define PSTR  132           // floats per q-row in partial: [m,l,pad,pad, acc(128)]
#define QSCALE 0.08838834764831845f  // 1/sqrt(128)

// LDS layout (bytes) — raw staging removed (R10): 24576 B total
#define OFF_QS    0          // 16*128*2  = 4096 (dead after qa load)
#define OFF_PS    4096       // 4*16*16*4 = 4096
#define OFF_KS    8192       // 4 waves * 4096 = 16384 (K bf16 [16][128] swz; V f32 [8][128] swz overlays)
#define OFF_ML    0          // overlay on dead Qs (512 B)
#define OFF_MERGE 8192       // overlay on Ks/Vs after last PV (16384 exact)
#define LDS_BYTES 24576

// quantization constants: Tk = cos((k-0.5)*pi/7) thresholds, squared; sin/cos(k*pi/7)
#define W1SQ 0.9504844339512096f   // cos^2(pi/14)
#define W2SQ 0.6112604669781572f   // cos^2(3pi/14)
#define W3SQ 0.1882550990706332f   // cos^2(5pi/14)
#define S1C  0.4338837391175581f   // sin(pi/7)
#define S2C  0.7818314824680298f   // sin(2pi/7)
#define S3C  0.9749279121818236f   // sin(3pi/7)
#define C1C  0.9009688679024191f   // cos(pi/7)
#define C2C  0.6234898018587336f   // cos(2pi/7)
#define C3C  0.2225209339563144f   // cos(3pi/7)
// last-angle (2*pi range) thresholds: cos((2k+1)pi/7), squared
#define B1SQ 0.8117449009293667f   // cos^2(pi/7)
#define B2SQ 0.0495155660487913f   // cos^2(3pi/7)
#define B3SQ 0.3887395330218429f   // cos^2(5pi/7)

// DPP controls
#define DPP_QP_XOR1 0xB1   // quad_perm(1,0,3,2)
#define DPP_QP_XOR2 0x4E   // quad_perm(2,3,0,1)
#define DPP_QP_SHL1 0x39   // quad_perm(1,2,3,0)
#define DPP_QP_SHR1 0x90   // quad_perm(0,0,1,2)
#define DPP_QP_SHR2 0x44   // quad_perm(0,1,0,1)
#define DPP_QP_BC0  0x00   // quad_perm(0,0,0,0)
#define DPP_QP_BC3  0xFF   // quad_perm(3,3,3,3)
#define DPP_HALF_MIRR 0x141  // i ^ 7 within row
#define DPP_MIRR      0x140  // i ^ 15 within row

template <int CTRL>
__device__ __forceinline__ float dpp0(float v) {
  return __int_as_float(__builtin_amdgcn_update_dpp(
      0, __float_as_int(v), CTRL, 0xF, 0xF, true));
}
// 16-lane-row butterfly reductions (softmax) — pure VALU
__device__ __forceinline__ float rmax16(float v) {
  v = fmaxf(v, dpp0<DPP_QP_XOR1>(v));
  v = fmaxf(v, dpp0<DPP_QP_XOR2>(v));
  v = fmaxf(v, dpp0<DPP_HALF_MIRR>(v));
  v = fmaxf(v, dpp0<DPP_MIRR>(v));
  return v;
}
__device__ __forceinline__ float rsum16(float v) {
  v += dpp0<DPP_QP_XOR1>(v);
  v += dpp0<DPP_QP_XOR2>(v);
  v += dpp0<DPP_HALF_MIRR>(v);
  v += dpp0<DPP_MIRR>(v);
  return v;
}
__device__ __forceinline__ float rdlane(float v, int l) {
  return __int_as_float(__builtin_amdgcn_readlane(__float_as_int(v), l));
}
__device__ __forceinline__ unsigned short f2bf(float f) {
  unsigned u = __float_as_uint(f);
  u += 0x7FFFu + ((u >> 16) & 1u);  // RNE
  return (unsigned short)(u >> 16);
}
__device__ __forceinline__ unsigned cvtpk(float lo, float hi) {
  unsigned r;
  asm("v_cvt_pk_bf16_f32 %0, %1, %2" : "=v"(r) : "v"(lo), "v"(hi));
  return r;
}

// Direct global load of a lane's 16 dims (64 contiguous bytes) for one
// 8-token granule: lane (tloc = lane>>3, o = lane&7) owns dims [o*16, o*16+16)
// of token tloc. 4x global_load_dwordx4; compiler inserts vmcnt waits at
// first USE, so issuing this one granule ahead hides HBM latency under
// the ~800-cycle decompress of the previous granule. (R10: replaces the
// LDS round-trip — DMA + vmcnt(0) drain + lgkmcnt fence + 4 ds_read_b128.)
__device__ __forceinline__ void loadx(float x[16], const float* __restrict__ g, int lane) {
  const int tloc = lane >> 3;
  const int o    = lane & 7;
  const float4* p = (const float4*)(g + tloc * DIM + o * 16);
  const float4 a = p[0], b = p[1], c = p[2], d = p[3];
  x[0]=a.x;  x[1]=a.y;  x[2]=a.z;  x[3]=a.w;
  x[4]=b.x;  x[5]=b.y;  x[6]=b.z;  x[7]=b.w;
  x[8]=c.x;  x[9]=c.y;  x[10]=c.z; x[11]=c.w;
  x[12]=d.x; x[13]=d.y; x[14]=d.z; x[15]=d.w;
}

// Per-lane polar compress+decompress of 8 tokens (one granule), x already
// in registers. No readlane, no data-dependent LDS, no divergence.
// K out: bf16 [16][128] rows q8*8+tloc, XOR-swizzled ^(tloc<<3) (ushort units).
// V out: f32 [8][128] rows tloc, XOR-swizzled ^(tloc<<2) (float units).
template <bool KOUT>
__device__ __forceinline__ void decomp8(
    const float (&x)[16], int lane,
    unsigned short* KsW, float* VsW, int q8)
{
  const int tloc = lane >> 3;       // token within granule (0..7)
  const int o    = lane & 7;        // 16-dim slice

  // ---- pass A: per-lane sum of squares, 8-lane suffix stitch (DPP only)
  float qa0 = 0.f, qa1 = 0.f;
#pragma unroll
  for (int i = 0; i < 16; i += 2) {
    qa0 = fmaf(x[i], x[i], qa0);
    qa1 = fmaf(x[i+1], x[i+1], qa1);
  }
  const float qs = qa0 + qa1;
  const float a1 = dpp0<DPP_QP_SHL1>(qs);
  const float t1 = qs + (((lane & 3) == 3) ? 0.f : a1);
  const float b1 = dpp0<DPP_QP_XOR2>(t1);
  const float t2 = t1 + (((lane & 3) < 2) ? b1 : 0.f);      // quad suffix-incl
  const float qt = dpp0<DPP_QP_BC0>(t2);                    // own quad total
  const float ot = dpp0<DPP_HALF_MIRR>(qt);                 // other quad total
  const float total = qt + ot;
  const float S = t2 + ((o < 4) ? ot : 0.f);                // suffix-incl across 8

  const float r = sqrtf(total);

  // ---- stage 1: quantize each dim, select sin/|cos|, lane sin-product
  float run = S, psin = 1.f, run14 = 0.f;
  float sv[16], cv[16];
#pragma unroll
  for (int i = 0; i < 16; ++i) {
    const float u = x[i] * x[i];
    if (i == 14) run14 = run;                 // ss at dim 126 (o==7 tail)
    const bool lo2 = u < W2SQ * run;          // |c| < T2  -> s in {2,3}
    const float thr = lo2 ? W3SQ : W1SQ;
    const bool bx = u < thr * run;
    const float ssin = lo2 ? (bx ? S3C : S2C) : (bx ? S1C : 0.f);
    float scos = lo2 ? (bx ? C3C : C2C) : (bx ? C1C : 1.f);
    scos = copysignf(scos, x[i]);             // idx >= 4 <=> x<0 <=> cos flips
    sv[i] = ssin; cv[i] = scos;
    psin *= ssin;
    run -= u;
  }
  // ---- 8-lane exclusive prefix-product stitch (DPP only)
  const float p1 = dpp0<DPP_QP_SHR1>(psin);
  const float e1 = psin * (((lane & 3) == 0) ? 1.f : p1);
  const float p2 = dpp0<DPP_QP_SHR2>(e1);
  const float e2 = e1 * (((lane & 3) < 2) ? 1.f : p2);      // quad prefix-incl
  const float pq = dpp0<DPP_QP_BC3>(e2);                    // own quad product
  const float po = dpp0<DPP_HALF_MIRR>(pq);                 // other quad product
  const float e3 = e2 * ((o >= 4) ? po : 1.f);              // full prefix-incl
  const float sh = dpp0<DPP_QP_SHR1>(e3);
  const float E = ((lane & 3) == 0) ? ((o < 4) ? 1.f : po) : sh;  // exclusive

  // ---- stage 2: outputs, with uniform blended tail for dims 126/127 (o==7)
  float rcum = r * E;
  const int T = q8 * 8 + tloc;
#pragma unroll
  for (int g = 0; g < 2; ++g) {
    float outv[8];
    float rc14 = rcum;
#pragma unroll
    for (int k = 0; k < 8; ++k) {
      const int i = 8 * g + k;
      if (i == 14) rc14 = rcum;
      outv[k] = rcum * cv[i];
      rcum *= sv[i];
    }
    if (g == 1) {
      // last angle has 2*pi range: idx from c126 thresholds, sign from x127
      const float u14 = x[14] * x[14];
      const bool neg = x[14] < 0.f;
      const bool cc1 = u14 < B1SQ * run14;
      const bool cc2 = u14 < B2SQ * run14;
      const bool cc3 = u14 > B3SQ * run14;
      const float cpos = cc2 ? -C3C : (cc1 ? C2C : 1.f);
      const float spos = cc2 ? S3C : (cc1 ? S2C : 0.f);
      const float cneg = cc3 ? -C1C : -C3C;
      const float sneg = cc3 ? S1C : S3C;
      const float cB = neg ? cneg : cpos;
      float sB = neg ? sneg : spos;
      sB = copysignf(sB, x[15]);
      const bool o7 = (o == 7);
      outv[6] = o7 ? rc14 * cB : outv[6];
      outv[7] = o7 ? rc14 * sB : outv[7];
    }
    if (KOUT) {
      uint4 w;
      w.x = cvtpk(outv[0], outv[1]);
      w.y = cvtpk(outv[2], outv[3]);
      w.z = cvtpk(outv[4], outv[5]);
      w.w = cvtpk(outv[6], outv[7]);
      // ushort idx: T*128 + ((o*16 + 8g) ^ (tloc<<3)) — 16B aligned
      *(uint4*)&KsW[T * 128 + ((o * 16 + 8 * g) ^ (tloc << 3))] = w;
    } else {
      // float idx: tloc*128 + ((o*16 + 8g + {0,4}) ^ (tloc<<2)) — 16B aligned
      const int f0 = (o * 16 + 8 * g) ^ (tloc << 2);
      *(float4*)&VsW[tloc * 128 + f0]       = make_float4(outv[0], outv[1], outv[2], outv[3]);
      *(float4*)&VsW[tloc * 128 + (f0 ^ 4)] = make_float4(outv[4], outv[5], outv[6], outv[7]);
    }
  }
}

__global__ __launch_bounds__(256, 2)   // known-good allocator setting (R7/R9 lesson:
                                       // any 128-total cap => massive scratch spill)
void attn_partial(const float* __restrict__ Q, const float* __restrict__ K,
                  const float* __restrict__ V, const float* __restrict__ noise,
                  float* __restrict__ part) {
  __shared__ __align__(16) char RAW[LDS_BYTES];
  unsigned short* Qs = (unsigned short*)(RAW + OFF_QS);
  float*          Ps = (float*)(RAW + OFF_PS);
  float2*         Ml = (float2*)(RAW + OFF_ML);   // overlays dead Qs

  const int tid  = threadIdx.x;
  const int lane = tid & 63;
  const int wv   = tid >> 6;
  const int h    = blockIdx.x / BPH;
  const int bh   = blockIdx.x % BPH;
  const int r16  = lane & 15, G = lane >> 4;

  unsigned short* KsW = (unsigned short*)(RAW + OFF_KS + wv * 4096);
  float* VsW = (float*)KsW;            // overlay: Ks dead after scores
  float* myP = Ps + wv * (CHK * NQ);

  const size_t hoff = (size_t)h * SEQT * DIM;
  const int t0 = bh * BTOK + wv * WTOK;
  const float* Kg = K + hoff + (size_t)t0 * DIM;
  const float* Vg = V + hoff + (size_t)t0 * DIM;

  // prologue: issue K granule 0 loads (tokens 0..7) before staging Q
  float xa[16], xb[16];
  loadx(xa, Kg, lane);
  {
    const float* Qh = Q + (size_t)h * NQ * DIM;
    for (int i = tid; i < NQ * DIM; i += 256)
      Qs[i] = f2bf(Qh[i] * QSCALE);
  }
  __syncthreads();   // Q ready

  bf16x8 qa[4];
#pragma unroll
  for (int c = 0; c < 4; ++c)
    qa[c] = *(const bf16x8*)&Qs[r16 * 128 + c * 32 + G * 8];

  f32x2 acc[NQ];
#pragma unroll
  for (int qq = 0; qq < NQ; ++qq) acc[qq] = (f32x2){0.f, 0.f};
  float m_r[4] = {-INFINITY, -INFINITY, -INFINITY, -INFINITY};
  float l_r[4] = {0.f, 0.f, 0.f, 0.f};

  const float* nh = noise + (size_t)h * NQ * SEQT + t0 + r16;

#pragma unroll 1
  for (int ch = 0; ch < 2; ++ch) {
    const float* KgC = Kg + ch * 2048;   // 16 tokens * 128 floats per chunk
    const float* VgC = Vg + ch * 2048;

    // ---- K decompress -> Ks bf16 (2 granules); loads issued 1 granule ahead
    loadx(xb, KgC + 1024, lane);              // K tok 8..15 of chunk
    decomp8<true>(xa, lane, KsW, VsW, 0);
    loadx(xa, VgC, lane);                     // V tok 0..7 of chunk
    decomp8<true>(xb, lane, KsW, VsW, 1);

    // ---- scores via MFMA, K=128 chained (Ks XOR-swizzled read)
    f32x4 d0 = {0.f, 0.f, 0.f, 0.f};
#pragma unroll
    for (int c = 0; c < 4; ++c) {
      bf16x8 b0 = *(const bf16x8*)&KsW[r16 * 128 + ((c * 32 + G * 8) ^ ((r16 & 7) << 3))];
      d0 = __builtin_amdgcn_mfma_f32_16x16x32_bf16(qa[c], b0, d0, 0, 0, 0);
    }
    const float* nt = nh + ch * CHK;
    float s0_[4];
#pragma unroll
    for (int rr = 0; rr < 4; ++rr)
      s0_[rr] = d0[rr] + nt[(size_t)(4 * G + rr) * SEQT];
    // ---- online softmax (quad G owns queries 4G..4G+3)
    float al_r[4];
#pragma unroll
    for (int rr = 0; rr < 4; ++rr) {
      float mt = rmax16(s0_[rr]);
      float mn = fmaxf(m_r[rr], mt);
      al_r[rr] = __expf(m_r[rr] - mn);
      m_r[rr] = mn;
    }
    float p0[4];
#pragma unroll
    for (int rr = 0; rr < 4; ++rr) {
      p0[rr] = __expf(s0_[rr] - m_r[rr]);
      l_r[rr] = l_r[rr] * al_r[rr] + rsum16(p0[rr]);
    }
    *(float4*)&myP[r16 * NQ + 4 * G] = make_float4(p0[0], p0[1], p0[2], p0[3]);
#pragma unroll
    for (int qq = 0; qq < NQ; ++qq) {
      float alq = rdlane(al_r[qq & 3], (qq >> 2) << 4);
      acc[qq] *= (f32x2){alq, alq};    // v_pk_mul_f32
    }

    // ---- V decompress (f32 -> Vs, overlays Ks) + PV, per 8-token granule
    loadx(xb, VgC + 1024, lane);              // V tok 8..15 of chunk
#pragma unroll 1
    for (int sc = 0; sc < 2; ++sc) {
      decomp8<false>(sc == 0 ? xa : xb, lane, KsW, VsW, 0);
      if (sc == 0 && ch == 0)
        loadx(xa, KgC + 2048, lane);          // next chunk K tok 0..7
#pragma unroll 2
      for (int tt = 0; tt < 8; ++tt) {
        float2 vh = *(const float2*)&VsW[tt * 128 + ((2 * lane) ^ (tt << 2))];
        f32x2 vh2 = {vh.x, vh.y};
        const float* pv = &myP[(sc * 8 + tt) * NQ];
        float4 pa = ((const float4*)pv)[0];
        float4 pb = ((const float4*)pv)[1];
        float4 pc = ((const float4*)pv)[2];
        float4 pd = ((const float4*)pv)[3];
        float pq[NQ] = {pa.x, pa.y, pa.z, pa.w, pb.x, pb.y, pb.z, pb.w,
                        pc.x, pc.y, pc.z, pc.w, pd.x, pd.y, pd.z, pd.w};
#pragma unroll
        for (int qq = 0; qq < NQ; ++qq)
          acc[qq] = __builtin_elementwise_fma((f32x2){pq[qq], pq[qq]}, vh2, acc[qq]);
      }
    }
  }

  // ---- block-level merge of the 4 wave states (online-softmax combine)
  if (r16 == 0) {
#pragma unroll
    for (int rr = 0; rr < 4; ++rr)
      Ml[wv * NQ + 4 * G + rr] = make_float2(m_r[rr], l_r[rr]);
  }
  __syncthreads();   // fences last Vs use before merge overlay
#pragma unroll
  for (int qq = 0; qq < NQ; ++qq) {
    float2 e0 = Ml[0 * NQ + qq], e1 = Ml[1 * NQ + qq];
    float2 e2 = Ml[2 * NQ + qq], e3 = Ml[3 * NQ + qq];
    float Mq = fmaxf(fmaxf(e0.x, e1.x), fmaxf(e2.x, e3.x));
    float own = (wv == 0) ? e0.x : ((wv == 1) ? e1.x : ((wv == 2) ? e2.x : e3.x));
    float al = __expf(own - Mq);
    acc[qq] *= (f32x2){al, al};
  }
  float* buf = (float*)(RAW + OFF_MERGE);   // overlays Ks/Vs (16384 B)
  if (wv >= 2) {
#pragma unroll
    for (int qq = 0; qq < NQ; ++qq)
      *(float2*)&buf[(wv - 2) * 2048 + qq * 128 + 2 * lane] =
          make_float2(acc[qq].x, acc[qq].y);
  }
  __syncthreads();
  if (wv < 2) {
#pragma unroll
    for (int qq = 0; qq < NQ; ++qq) {
      float2 t = *(const float2*)&buf[wv * 2048 + qq * 128 + 2 * lane];
      acc[qq] += (f32x2){t.x, t.y};
    }
  }
  __syncthreads();
  if (wv == 1) {
#pragma unroll
    for (int qq = 0; qq < NQ; ++qq)
      *(float2*)&buf[qq * 128 + 2 * lane] = make_float2(acc[qq].x, acc[qq].y);
  }
  __syncthreads();
  if (wv == 0) {
    float* P = part + ((size_t)h * NPART + bh) * (NQ * PSTR);
#pragma unroll
    for (int qq = 0; qq < NQ; ++qq) {
      float2 t = *(const float2*)&buf[qq * 128 + 2 * lane];
      *(float2*)&P[qq * PSTR + 4 + 2 * lane] =
          make_float2(acc[qq].x + t.x, acc[qq].y + t.y);
      float2 e0 = Ml[0 * NQ + qq], e1 = Ml[1 * NQ + qq];
      float2 e2 = Ml[2 * NQ + qq], e3 = Ml[3 * NQ + qq];
      float Mq = fmaxf(fmaxf(e0.x, e1.x), fmaxf(e2.x, e3.x));
      float Lq = e0.y * __expf(e0.x - Mq) + e1.y * __expf(e1.x - Mq) +
                 e2.y * __expf(e2.x - Mq) + e3.y * __expf(e3.x - Mq);
      if (lane == 0) *(float2*)&P[qq * PSTR] = make_float2(Mq, Lq);
    }
  }
}

__global__ __launch_bounds__(128)
void attn_reduce(const float* __restrict__ part, float* __restrict__ out) {
  __shared__ float wgt[NPART];
  __shared__ float Lsh;
  const int tid = threadIdx.x;
  const int h = blockIdx.x >> 4;
  const int q = blockIdx.x & 15;
  const float* P = part + (size_t)h * NPART * NQ * PSTR;
  if (tid < NPART) {
    float2 ml = *(const float2*)&P[((size_t)tid * NQ + q) * PSTR];
    float M = ml.x;
#pragma unroll
    for (int off = 1; off < 64; off <<= 1)
      M = fmaxf(M, __shfl_xor(M, off, 64));
    float w = __expf(ml.x - M);
    wgt[tid] = w;
    float L = ml.y * w;
#pragma unroll
    for (int off = 1; off < 64; off <<= 1)
      L += __shfl_xor(L, off, 64);
    if (tid == 0) Lsh = L;
  }
  __syncthreads();
  const float* A = P + (size_t)q * PSTR + 4 + tid;
  float o = 0.f;
#pragma unroll 8
  for (int c = 0; c < NPART; ++c)
    o = fmaf(wgt[c], A[(size_t)c * NQ * PSTR], o);
  out[((size_t)h * NQ + q) * DIM + tid] = o * (1.0f / Lsh);
}

extern "C" void kernel_launch(void* const* d_in, const int* in_sizes, int n_in,
                              void* d_out, int out_size, void* d_ws, size_t ws_size,
                              hipStream_t stream) {
  (void)in_sizes; (void)n_in; (void)out_size; (void)ws_size;
  const float* Q = (const float*)d_in[0];
  const float* K = (const float*)d_in[1];
  const float* V = (const float*)d_in[2];
  const float* noise = (const float*)d_in[3];
  float* part = (float*)d_ws;  // 32*64*16*132*4 B = 17.3 MB
  attn_partial<<<dim3(HEADS * BPH), dim3(256), 0, stream>>>(Q, K, V, noise, part);
  attn_reduce<<<dim3(HEADS * NQ), dim3(128), 0, stream>>>(part, (float*)d_out);
}

// Round 14
// 300.202 us; speedup vs baseline: 1.1485x; 1.0309x over previous
//
#include <hip/hip_runtime.h>
#include <math.h>

typedef __attribute__((ext_vector_type(8))) short bf16x8;
typedef __attribute__((ext_vector_type(4))) short bf16x4;
typedef __attribute__((ext_vector_type(4))) float f32x4;

#define HEADS 32
#define SEQT  8192
#define DIM   128
#define NQ    16
#define BPH   64            // blocks per head
#define BTOK  128           // tokens per block
#define WTOK  32            // tokens per wave (= one K=32 PV MFMA pass)
#define NPART BPH
#define PSTR  132           // floats per q-row in partial: [m,l,pad,pad, acc(128)]
#define QSCALE 0.08838834764831845f  // 1/sqrt(128)

// LDS layout (bytes). P/V stored transposed bf16 for MFMA-PV fragments.
#define OFF_QS    0          // 16*128*2 = 4096 (dead after qa load; Ml overlays)
#define OFF_PL    4096       // 4 waves * 16*40*2 = 5120  (P bf16 [16 q][40 tok-pad])
#define OFF_KS    9216       // 4 waves * 4096 = 16384    (K bf16 [16][128] swz)
#define OFF_VS    25600      // 4 waves * 128*40*2 = 40960 (V bf16 [128 d][40 tok-pad] swz)
#define OFF_ML    0          // overlay on dead Qs (512 B)
#define OFF_MERGE 9216       // overlay on Ks/Vs after PV (needs 16896)
#define LDS_BYTES 66560

// quantization constants: Tk = cos((k-0.5)*pi/7) thresholds, squared; sin/cos(k*pi/7)
#define W1SQ 0.9504844339512096f   // cos^2(pi/14)
#define W2SQ 0.6112604669781572f   // cos^2(3pi/14)
#define W3SQ 0.1882550990706332f   // cos^2(5pi/14)
#define S1C  0.4338837391175581f   // sin(pi/7)
#define S2C  0.7818314824680298f   // sin(2pi/7)
#define S3C  0.9749279121818236f   // sin(3pi/7)
#define C1C  0.9009688679024191f   // cos(pi/7)
#define C2C  0.6234898018587336f   // cos(2pi/7)
#define C3C  0.2225209339563144f   // cos(3pi/7)
// last-angle (2*pi range) thresholds: cos((2k+1)pi/7), squared
#define B1SQ 0.8117449009293667f   // cos^2(pi/7)
#define B2SQ 0.0495155660487913f   // cos^2(3pi/7)
#define B3SQ 0.3887395330218429f   // cos^2(5pi/7)

// DPP controls
#define DPP_QP_XOR1 0xB1   // quad_perm(1,0,3,2)
#define DPP_QP_XOR2 0x4E   // quad_perm(2,3,0,1)
#define DPP_QP_SHL1 0x39   // quad_perm(1,2,3,0)
#define DPP_QP_SHR1 0x90   // quad_perm(0,0,1,2)
#define DPP_QP_SHR2 0x44   // quad_perm(0,1,0,1)
#define DPP_QP_BC0  0x00   // quad_perm(0,0,0,0)
#define DPP_QP_BC3  0xFF   // quad_perm(3,3,3,3)
#define DPP_HALF_MIRR 0x141  // i ^ 7 within row
#define DPP_MIRR      0x140  // i ^ 15 within row

template <int CTRL>
__device__ __forceinline__ float dpp0(float v) {
  return __int_as_float(__builtin_amdgcn_update_dpp(
      0, __float_as_int(v), CTRL, 0xF, 0xF, true));
}
// 16-lane-row butterfly reductions (softmax) — pure VALU
__device__ __forceinline__ float rmax16(float v) {
  v = fmaxf(v, dpp0<DPP_QP_XOR1>(v));
  v = fmaxf(v, dpp0<DPP_QP_XOR2>(v));
  v = fmaxf(v, dpp0<DPP_HALF_MIRR>(v));
  v = fmaxf(v, dpp0<DPP_MIRR>(v));
  return v;
}
__device__ __forceinline__ float rsum16(float v) {
  v += dpp0<DPP_QP_XOR1>(v);
  v += dpp0<DPP_QP_XOR2>(v);
  v += dpp0<DPP_HALF_MIRR>(v);
  v += dpp0<DPP_MIRR>(v);
  return v;
}
__device__ __forceinline__ unsigned short f2bf(float f) {
  unsigned u = __float_as_uint(f);
  u += 0x7FFFu + ((u >> 16) & 1u);  // RNE
  return (unsigned short)(u >> 16);
}
__device__ __forceinline__ unsigned cvtpk(float lo, float hi) {
  unsigned r;
  asm("v_cvt_pk_bf16_f32 %0, %1, %2" : "=v"(r) : "v"(lo), "v"(hi));
  return r;
}

// Direct global load of a lane's 16 dims (64 contiguous bytes) for one
// 8-token granule: lane (tloc = lane>>3, o = lane&7) owns dims [o*16, o*16+16)
// of token tloc. Issued one granule ahead; compiler inserts vmcnt at first use.
__device__ __forceinline__ void loadx(float x[16], const float* __restrict__ g, int lane) {
  const int tloc = lane >> 3;
  const int o    = lane & 7;
  const float4* p = (const float4*)(g + tloc * DIM + o * 16);
  const float4 a = p[0], b = p[1], c = p[2], d = p[3];
  x[0]=a.x;  x[1]=a.y;  x[2]=a.z;  x[3]=a.w;
  x[4]=b.x;  x[5]=b.y;  x[6]=b.z;  x[7]=b.w;
  x[8]=c.x;  x[9]=c.y;  x[10]=c.z; x[11]=c.w;
  x[12]=d.x; x[13]=d.y; x[14]=d.z; x[15]=d.w;
}

// Per-lane polar compress+decompress of 8 tokens (one granule), x in regs.
// K out (KOUT=1): bf16 [16][128] rows tbase+tloc, XOR-swz ^(tloc<<3) (ushort units)
//   — feeds the scores MFMA B-operand (unchanged from R10, verified passing).
// V out (KOUT=0): bf16 TRANSPOSED [128 d][40 tok] rows, tok-slot XOR-swz
//   ^( (d>>4)<<2 ) — feeds the PV MFMA B-operand (lane: col=l&15, k=8*(l>>4)+j).
template <bool KOUT>
__device__ __forceinline__ void decomp8(
    const float (&x)[16], int lane,
    unsigned short* KsW, unsigned short* Vl, int tbase)
{
  const int tloc = lane >> 3;       // token within granule (0..7)
  const int o    = lane & 7;        // 16-dim slice

  // ---- pass A: per-lane sum of squares, 8-lane suffix stitch (DPP only)
  float qa0 = 0.f, qa1 = 0.f;
#pragma unroll
  for (int i = 0; i < 16; i += 2) {
    qa0 = fmaf(x[i], x[i], qa0);
    qa1 = fmaf(x[i+1], x[i+1], qa1);
  }
  const float qs = qa0 + qa1;
  const float a1 = dpp0<DPP_QP_SHL1>(qs);
  const float t1 = qs + (((lane & 3) == 3) ? 0.f : a1);
  const float b1 = dpp0<DPP_QP_XOR2>(t1);
  const float t2 = t1 + (((lane & 3) < 2) ? b1 : 0.f);      // quad suffix-incl
  const float qt = dpp0<DPP_QP_BC0>(t2);                    // own quad total
  const float ot = dpp0<DPP_HALF_MIRR>(qt);                 // other quad total
  const float total = qt + ot;
  const float S = t2 + ((o < 4) ? ot : 0.f);                // suffix-incl across 8

  const float r = sqrtf(total);

  // ---- stage 1: quantize each dim, select sin/|cos|, lane sin-product
  float run = S, psin = 1.f, run14 = 0.f;
  float sv[16], cv[16];
#pragma unroll
  for (int i = 0; i < 16; ++i) {
    const float u = x[i] * x[i];
    if (i == 14) run14 = run;                 // ss at dim 126 (o==7 tail)
    const bool lo2 = u < W2SQ * run;          // |c| < T2  -> s in {2,3}
    const float thr = lo2 ? W3SQ : W1SQ;
    const bool bx = u < thr * run;
    const float ssin = lo2 ? (bx ? S3C : S2C) : (bx ? S1C : 0.f);
    float scos = lo2 ? (bx ? C3C : C2C) : (bx ? C1C : 1.f);
    scos = copysignf(scos, x[i]);             // idx >= 4 <=> x<0 <=> cos flips
    sv[i] = ssin; cv[i] = scos;
    psin *= ssin;
    run -= u;
  }
  // ---- 8-lane exclusive prefix-product stitch (DPP only)
  const float p1 = dpp0<DPP_QP_SHR1>(psin);
  const float e1 = psin * (((lane & 3) == 0) ? 1.f : p1);
  const float p2 = dpp0<DPP_QP_SHR2>(e1);
  const float e2 = e1 * (((lane & 3) < 2) ? 1.f : p2);      // quad prefix-incl
  const float pq = dpp0<DPP_QP_BC3>(e2);                    // own quad product
  const float po = dpp0<DPP_HALF_MIRR>(pq);                 // other quad product
  const float e3 = e2 * ((o >= 4) ? po : 1.f);              // full prefix-incl
  const float sh = dpp0<DPP_QP_SHR1>(e3);
  const float E = ((lane & 3) == 0) ? ((o < 4) ? 1.f : po) : sh;  // exclusive

  // ---- stage 2: outputs, with uniform blended tail for dims 126/127 (o==7)
  float rcum = r * E;
  const int T = tbase + tloc;
#pragma unroll
  for (int g = 0; g < 2; ++g) {
    float outv[8];
    float rc14 = rcum;
#pragma unroll
    for (int k = 0; k < 8; ++k) {
      const int i = 8 * g + k;
      if (i == 14) rc14 = rcum;
      outv[k] = rcum * cv[i];
      rcum *= sv[i];
    }
    if (g == 1) {
      // last angle has 2*pi range: idx from c126 thresholds, sign from x127
      const float u14 = x[14] * x[14];
      const bool neg = x[14] < 0.f;
      const bool cc1 = u14 < B1SQ * run14;
      const bool cc2 = u14 < B2SQ * run14;
      const bool cc3 = u14 > B3SQ * run14;
      const float cpos = cc2 ? -C3C : (cc1 ? C2C : 1.f);
      const float spos = cc2 ? S3C : (cc1 ? S2C : 0.f);
      const float cneg = cc3 ? -C1C : -C3C;
      const float sneg = cc3 ? S1C : S3C;
      const float cB = neg ? cneg : cpos;
      float sB = neg ? sneg : spos;
      sB = copysignf(sB, x[15]);
      const bool o7 = (o == 7);
      outv[6] = o7 ? rc14 * cB : outv[6];
      outv[7] = o7 ? rc14 * sB : outv[7];
    }
    if (KOUT) {
      uint4 w;
      w.x = cvtpk(outv[0], outv[1]);
      w.y = cvtpk(outv[2], outv[3]);
      w.z = cvtpk(outv[4], outv[5]);
      w.w = cvtpk(outv[6], outv[7]);
      // ushort idx: T*128 + ((o*16 + 8g) ^ (tloc<<3)) — 16B aligned
      *(uint4*)&KsW[(T & 15) * 128 + ((o * 16 + 8 * g) ^ (tloc << 3))] = w;
    } else {
      // transposed: Vl[d][ tok ^ ((d>>4)<<2) ], d = o*16 + 8g + k, row = 40 us
      const int ps = T ^ (o << 2);            // (d>>4) == o for all k here
#pragma unroll
      for (int k = 0; k < 8; k += 2) {
        const unsigned u = cvtpk(outv[k], outv[k+1]);
        Vl[(o * 16 + 8 * g + k)     * 40 + ps] = (unsigned short)u;
        Vl[(o * 16 + 8 * g + k + 1) * 40 + ps] = (unsigned short)(u >> 16);
      }
    }
  }
}

__global__ __launch_bounds__(256, 2)   // known-good allocator setting (R7/R9:
                                       // any 128-total cap => massive scratch spill)
void attn_partial(const float* __restrict__ Q, const float* __restrict__ K,
                  const float* __restrict__ V, const float* __restrict__ noise,
                  float* __restrict__ part) {
  __shared__ __align__(16) char RAW[LDS_BYTES];
  unsigned short* Qs = (unsigned short*)(RAW + OFF_QS);
  float2*         Ml = (float2*)(RAW + OFF_ML);   // overlays dead Qs

  const int tid  = threadIdx.x;
  const int lane = tid & 63;
  const int wv   = tid >> 6;
  const int h    = blockIdx.x / BPH;
  const int bh   = blockIdx.x % BPH;
  const int r16  = lane & 15, G = lane >> 4;

  unsigned short* Pl  = (unsigned short*)(RAW + OFF_PL) + wv * 640;   // [16][40]
  unsigned short* KsW = (unsigned short*)(RAW + OFF_KS) + wv * 2048;  // [16][128]
  unsigned short* Vl  = (unsigned short*)(RAW + OFF_VS) + wv * 5120;  // [128][40]

  const size_t hoff = (size_t)h * SEQT * DIM;
  const int t0 = bh * BTOK + wv * WTOK;
  const float* Kg = K + hoff + (size_t)t0 * DIM;
  const float* Vg = V + hoff + (size_t)t0 * DIM;

  // prologue: issue K granule 0 loads before staging Q
  float xa[16], xb[16];
  loadx(xa, Kg, lane);
  {
    const float* Qh = Q + (size_t)h * NQ * DIM;
    for (int i = tid; i < NQ * DIM; i += 256)
      Qs[i] = f2bf(Qh[i] * QSCALE);
  }
  __syncthreads();   // Q ready

  bf16x8 qa[4];
#pragma unroll
  for (int c = 0; c < 4; ++c)
    qa[c] = *(const bf16x8*)&Qs[r16 * 128 + c * 32 + G * 8];

  const float* nh = noise + (size_t)h * NQ * SEQT + t0 + r16;

  // ================= K phase: scores for both 16-token chunks =================
  loadx(xb, Kg + 1024, lane);                    // K tok 8..15
  decomp8<true>(xa, lane, KsW, Vl, 0);
  loadx(xa, Kg + 2048, lane);                    // K tok 16..23
  decomp8<true>(xb, lane, KsW, Vl, 8);

  f32x4 dA = {0.f, 0.f, 0.f, 0.f};
#pragma unroll
  for (int c = 0; c < 4; ++c) {
    bf16x8 b0 = *(const bf16x8*)&KsW[r16 * 128 + ((c * 32 + G * 8) ^ ((r16 & 7) << 3))];
    dA = __builtin_amdgcn_mfma_f32_16x16x32_bf16(qa[c], b0, dA, 0, 0, 0);
  }
  float sA[4];
#pragma unroll
  for (int rr = 0; rr < 4; ++rr)
    sA[rr] = dA[rr] + nh[(size_t)(4 * G + rr) * SEQT];

  loadx(xb, Kg + 3072, lane);                    // K tok 24..31
  decomp8<true>(xa, lane, KsW, Vl, 0);
  loadx(xa, Vg, lane);                           // V tok 0..7
  decomp8<true>(xb, lane, KsW, Vl, 8);

  f32x4 dB = {0.f, 0.f, 0.f, 0.f};
#pragma unroll
  for (int c = 0; c < 4; ++c) {
    bf16x8 b0 = *(const bf16x8*)&KsW[r16 * 128 + ((c * 32 + G * 8) ^ ((r16 & 7) << 3))];
    dB = __builtin_amdgcn_mfma_f32_16x16x32_bf16(qa[c], b0, dB, 0, 0, 0);
  }
  float sB[4];
#pragma unroll
  for (int rr = 0; rr < 4; ++rr)
    sB[rr] = dB[rr] + nh[(size_t)(4 * G + rr) * SEQT + 16];

  // ============ single-pass softmax over the wave's 32 tokens ============
  float mt[4], l_r[4];
#pragma unroll
  for (int rr = 0; rr < 4; ++rr) {
    mt[rr] = fmaxf(rmax16(sA[rr]), rmax16(sB[rr]));
    const float pA = __expf(sA[rr] - mt[rr]);
    const float pB = __expf(sB[rr] - mt[rr]);
    l_r[rr] = rsum16(pA) + rsum16(pB);
    // store P transposed bf16: row q = 4G+rr, tok = r16 (A) / r16+16 (B)
    const unsigned u = cvtpk(pA, pB);
    Pl[(4 * G + rr) * 40 + r16]      = (unsigned short)u;
    Pl[(4 * G + rr) * 40 + 16 + r16] = (unsigned short)(u >> 16);
  }

  // ================= V phase: decompress all 32 tokens =================
  loadx(xb, Vg + 1024, lane);                    // V tok 8..15
  decomp8<false>(xa, lane, KsW, Vl, 0);
  loadx(xa, Vg + 2048, lane);                    // V tok 16..23
  decomp8<false>(xb, lane, KsW, Vl, 8);
  loadx(xb, Vg + 3072, lane);                    // V tok 24..31
  decomp8<false>(xa, lane, KsW, Vl, 16);
  decomp8<false>(xb, lane, KsW, Vl, 24);

  // ================= PV via MFMA: O[16q x 128d] = P · V =================
  // A-frag: lane reads P[q=l&15][tok 8*(l>>4) .. +8] (16B, row pad 40 -> 2-way)
  const bf16x8 pf = *(const bf16x8*)&Pl[r16 * 40 + 8 * G];
  f32x4 acc[8];
#pragma unroll
  for (int dt = 0; dt < 8; ++dt) acc[dt] = (f32x4){0.f, 0.f, 0.f, 0.f};
#pragma unroll
  for (int dt = 0; dt < 8; ++dt) {
    // B-frag: lane needs V[tok=8*(l>>4)+j][d=dt*16+(l&15)], j=0..7, from the
    // tok-swizzled layout: block base 8*(G^(dt>>1)); odd dt swaps b64 halves.
    const int gb = G ^ (dt >> 1);
    const int sw = (dt & 1) << 2;
    const unsigned short* vr = &Vl[(dt * 16 + r16) * 40 + 8 * gb];
    const bf16x4 v0 = *(const bf16x4*)&vr[sw];       // j = 0..3
    const bf16x4 v1 = *(const bf16x4*)&vr[4 - sw];   // j = 4..7
    const bf16x8 vf = __builtin_shufflevector(v0, v1, 0, 1, 2, 3, 4, 5, 6, 7);
    acc[dt] = __builtin_amdgcn_mfma_f32_16x16x32_bf16(pf, vf, acc[dt], 0, 0, 0);
  }
  // acc[dt][reg] = O[q = 4G+reg][d = dt*16 + r16]  (C/D: col=l&15, row=4*(l>>4)+reg)

  // ---- block-level merge of the 4 wave states (online-softmax combine)
  if (r16 == 0) {
#pragma unroll
    for (int rr = 0; rr < 4; ++rr)
      Ml[wv * NQ + 4 * G + rr] = make_float2(mt[rr], l_r[rr]);
  }
  __syncthreads();   // fences last P/Ks/V use before merge overlay
  float al[4];
#pragma unroll
  for (int reg = 0; reg < 4; ++reg) {
    const int q = 4 * G + reg;
    float2 e0 = Ml[0 * NQ + q], e1 = Ml[1 * NQ + q];
    float2 e2 = Ml[2 * NQ + q], e3 = Ml[3 * NQ + q];
    float Mq = fmaxf(fmaxf(e0.x, e1.x), fmaxf(e2.x, e3.x));
    float own = (wv == 0) ? e0.x : ((wv == 1) ? e1.x : ((wv == 2) ? e2.x : e3.x));
    al[reg] = __expf(own - Mq);
  }
#pragma unroll
  for (int dt = 0; dt < 8; ++dt)
#pragma unroll
    for (int reg = 0; reg < 4; ++reg) acc[dt][reg] *= al[reg];

  float* buf = (float*)(RAW + OFF_MERGE);   // [2][16 q][132 d] overlay
  if (wv >= 2) {
#pragma unroll
    for (int dt = 0; dt < 8; ++dt)
#pragma unroll
      for (int reg = 0; reg < 4; ++reg)
        buf[(wv - 2) * 2112 + (4 * G + reg) * 132 + dt * 16 + r16] = acc[dt][reg];
  }
  __syncthreads();
  if (wv < 2) {
#pragma unroll
    for (int dt = 0; dt < 8; ++dt)
#pragma unroll
      for (int reg = 0; reg < 4; ++reg)
        acc[dt][reg] += buf[wv * 2112 + (4 * G + reg) * 132 + dt * 16 + r16];
  }
  __syncthreads();
  if (wv == 1) {
#pragma unroll
    for (int dt = 0; dt < 8; ++dt)
#pragma unroll
      for (int reg = 0; reg < 4; ++reg)
        buf[(4 * G + reg) * 132 + dt * 16 + r16] = acc[dt][reg];
  }
  __syncthreads();
  if (wv == 0) {
    float* P = part + ((size_t)h * NPART + bh) * (NQ * PSTR);
#pragma unroll
    for (int dt = 0; dt < 8; ++dt)
#pragma unroll
      for (int reg = 0; reg < 4; ++reg) {
        const int q = 4 * G + reg, d = dt * 16 + r16;
        P[q * PSTR + 4 + d] = acc[dt][reg] + buf[q * 132 + d];
      }
    // header (uniform across lanes; lane 0 stores)
#pragma unroll
    for (int qq = 0; qq < NQ; ++qq) {
      float2 e0 = Ml[0 * NQ + qq], e1 = Ml[1 * NQ + qq];
      float2 e2 = Ml[2 * NQ + qq], e3 = Ml[3 * NQ + qq];
      float Mq = fmaxf(fmaxf(e0.x, e1.x), fmaxf(e2.x, e3.x));
      float Lq = e0.y * __expf(e0.x - Mq) + e1.y * __expf(e1.x - Mq) +
                 e2.y * __expf(e2.x - Mq) + e3.y * __expf(e3.x - Mq);
      if (lane == 0) *(float2*)&P[qq * PSTR] = make_float2(Mq, Lq);
    }
  }
}

__global__ __launch_bounds__(128)
void attn_reduce(const float* __restrict__ part, float* __restrict__ out) {
  __shared__ float wgt[NPART];
  __shared__ float Lsh;
  const int tid = threadIdx.x;
  const int h = blockIdx.x >> 4;
  const int q = blockIdx.x & 15;
  const float* P = part + (size_t)h * NPART * NQ * PSTR;
  if (tid < NPART) {
    float2 ml = *(const float2*)&P[((size_t)tid * NQ + q) * PSTR];
    float M = ml.x;
#pragma unroll
    for (int off = 1; off < 64; off <<= 1)
      M = fmaxf(M, __shfl_xor(M, off, 64));
    float w = __expf(ml.x - M);
    wgt[tid] = w;
    float L = ml.y * w;
#pragma unroll
    for (int off = 1; off < 64; off <<= 1)
      L += __shfl_xor(L, off, 64);
    if (tid == 0) Lsh = L;
  }
  __syncthreads();
  const float* A = P + (size_t)q * PSTR + 4 + tid;
  float o = 0.f;
#pragma unroll 8
  for (int c = 0; c < NPART; ++c)
    o = fmaf(wgt[c], A[(size_t)c * NQ * PSTR], o);
  out[((size_t)h * NQ + q) * DIM + tid] = o * (1.0f / Lsh);
}

extern "C" void kernel_launch(void* const* d_in, const int* in_sizes, int n_in,
                              void* d_out, int out_size, void* d_ws, size_t ws_size,
                              hipStream_t stream) {
  (void)in_sizes; (void)n_in; (void)out_size; (void)ws_size;
  const float* Q = (const float*)d_in[0];
  const float* K = (const float*)d_in[1];
  const float* V = (const float*)d_in[2];
  const float* noise = (const float*)d_in[3];
  float* part = (float*)d_ws;  // 32*64*16*132*4 B = 17.3 MB
  attn_partial<<<dim3(HEADS * BPH), dim3(256), 0, stream>>>(Q, K, V, noise, part);
  attn_reduce<<<dim3(HEADS * NQ), dim3(128), 0, stream>>>(part, (float*)d_out);
}